// Round 1
// baseline (5177.612 us; speedup 1.0000x reference)
//
#include <hip/hip_runtime.h>
#include <cfloat>
#include <cstdint>
#include <cstddef>

typedef _Float16 f16;
typedef _Float16 f16x2v __attribute__((ext_vector_type(2)));
typedef _Float16 f16x4v __attribute__((ext_vector_type(4)));
typedef _Float16 f16x8v __attribute__((ext_vector_type(8)));
typedef float    f32x4v __attribute__((ext_vector_type(4)));
typedef unsigned u32x2v __attribute__((ext_vector_type(2)));

#define LDP 72          // padded f16 row stride (b128-aligned, breaks bank conflicts)
#define SWEEPS 8        // one-sided Jacobi sweeps

// ===================== ws layout (bytes) =====================
#define OFF_U      ((size_t)0)                   // f16 [8192][64][64]  row-major (rows i, cols = eigvecs)
#define OFF_UT     (OFF_U + (size_t)67108864)    // f16 [8192][64][64]  U^T row-major
#define OFF_LAM    (OFF_UT + (size_t)67108864)   // float2 [8192][64]   (lambda, log lambda)
#define OFF_MPART  (OFF_LAM + (size_t)4194304)   // float [64][4096]
#define OFF_JPART  (OFF_MPART + (size_t)1048576) // float [1024][4096]
#define OFF_MEAN   (OFF_JPART + (size_t)16777216)
#define OFF_C12    (OFF_MEAN + 16384)
#define OFF_JSUM   (OFF_C12 + 16384)
#define OFF_S      (OFF_JSUM + 16384)            // sqrt(bias), fp32
#define OFF_P16    (OFF_S + 16384)               // P = S * isqrt(mean), f16 row-major
#define OFF_D16    (OFF_P16 + 8192)              // d matrix, f16 row-major
#define OFF_STATE  (OFF_D16 + 8192)              // [nu, tau, lw0, ...]
#define WS_NEEDED  (OFF_STATE + 256)

// ===================== small block helpers (256-thread kernels) =====================
__device__ __forceinline__ float bred256(float v, float* scr) {
    int tid = threadIdx.x;
    scr[tid] = v; __syncthreads();
    #pragma unroll
    for (int s = 128; s >= 1; s >>= 1) {
        if (tid < s) scr[tid] += scr[tid + s];
        __syncthreads();
    }
    float r = scr[0]; __syncthreads();
    return r;
}

// C = (accum ? C : 0) + scale * A*B   (64x64, generic pointers; has entry+exit barriers)
__device__ void g64(const float* A, const float* B, float* C, float scale, bool accum) {
    __syncthreads();
    for (int idx = threadIdx.x; idx < 4096; idx += blockDim.x) {
        int r = idx >> 6, c = idx & 63;
        float s = 0.0f;
        #pragma unroll 8
        for (int k = 0; k < 64; ++k) s = fmaf(A[(r << 6) + k], B[(k << 6) + c], s);
        C[idx] = (accum ? C[idx] : 0.0f) + scale * s;
    }
    __syncthreads();
}

// ===================== batch-mean reduction =====================
__global__ __launch_bounds__(256) void k_mean_part(const float* __restrict__ X, float* __restrict__ part) {
    int p = blockIdx.x, tid = threadIdx.x;
    float acc[16];
    #pragma unroll
    for (int t = 0; t < 16; ++t) acc[t] = 0.0f;
    const float* base = X + (size_t)p * 128 * 4096;
    for (int m = 0; m < 128; ++m) {
        const float* Xb = base + (size_t)m * 4096;
        #pragma unroll
        for (int t = 0; t < 16; ++t) acc[t] += Xb[t * 256 + tid];
    }
    #pragma unroll
    for (int t = 0; t < 16; ++t) part[(size_t)p * 4096 + t * 256 + tid] = acc[t];
}

__global__ __launch_bounds__(256) void k_mean_fin(const float* __restrict__ part, float* __restrict__ mean) {
    int e = blockIdx.x * 256 + threadIdx.x;
    float s = 0.0f;
    for (int p = 0; p < 64; ++p) s += part[(size_t)p * 4096 + e];
    mean[e] = s * (1.0f / 8192.0f);
}

__global__ __launch_bounds__(64) void k_init(float* __restrict__ state) {
    if (threadIdx.x == 0) { state[0] = 1.0f; state[1] = FLT_MAX; state[2] = 0.0f; }
}

// ===================== sqrt(bias) via coupled Newton-Schulz =====================
__global__ __launch_bounds__(256) void k_bias_sqrt(const float* __restrict__ bias, float* __restrict__ S) {
    __shared__ float buf[4 * 4096];   // exactly 64 KB
    float *B0 = buf, *B1 = buf + 4096, *B2 = buf + 8192, *B3 = buf + 12288;
    int tid = threadIdx.x;
    float p = 0.0f;
    for (int idx = tid; idx < 4096; idx += 256) { float v = bias[idx]; B0[idx] = v; p += v * v; }
    float fr2 = bred256(p, B1);       // B1 used as scratch before it becomes Z
    float g = sqrtf(fr2);             // gamma = ||bias||_F >= lambda_max
    float invg = 1.0f / g;
    for (int idx = tid; idx < 4096; idx += 256) {
        B0[idx] *= invg;
        B1[idx] = (idx % 65 == 0) ? 1.0f : 0.0f;
    }
    float *pY = B0, *pZ = B1, *pT = B2, *pS = B3;
    for (int it = 0; it < 10; ++it) {
        g64(pZ, pY, pT, -0.5f, false);                    // T = -0.5 Z Y
        for (int idx = tid; idx < 4096; idx += 256)
            if (idx % 65 == 0) pT[idx] += 1.5f;           // T = (3I - ZY)/2
        g64(pY, pT, pS, 1.0f, false);                     // newY
        float* oldY = pY; pY = pS; pS = oldY;
        g64(pT, pZ, pS, 1.0f, false);                     // newZ (into old Y)
        float* oldZ = pZ; pZ = pS; pS = oldZ;
    }
    float sg = sqrtf(g);
    __syncthreads();
    for (int idx = tid; idx < 4096; idx += 256) S[idx] = sg * pY[idx];
}

// ===================== VALU-pipe cross-lane helpers (k_eig) =====================
// xor-mask exchange primitives that do NOT touch the DS pipe:
//   quad_perm DPP: xor1=0xB1 [1,0,3,2], xor2=0x4E [2,3,0,1], xor3=0x1B [3,2,1,0]
//   row_half_mirror 0x141 = xor7 (within 8), row_ror:8 0x128 = xor8 (within 16)
//   permlane16_swap = xor16, permlane32_swap = xor32 (adjacent-row swap + cndmask)
template <int CTRL>
__device__ __forceinline__ float dppf(float x) {
    return __builtin_bit_cast(float, __builtin_amdgcn_update_dpp(
        0, __builtin_bit_cast(int, x), CTRL, 0xF, 0xF, true));
}

__device__ __forceinline__ float pl16(float x, bool odd16) {
#if __has_builtin(__builtin_amdgcn_permlane16_swap)
    u32x2v r = __builtin_amdgcn_permlane16_swap(
        __builtin_bit_cast(unsigned, x), __builtin_bit_cast(unsigned, x), false, false);
    // new_vdst odd 16-rows hold src even-row data (lane-16); new_src even rows hold lane+16
    return __builtin_bit_cast(float, odd16 ? r[0] : r[1]);
#else
    return __shfl_xor(x, 16, 64);
#endif
}

__device__ __forceinline__ float pl32(float x, bool hi32) {
#if __has_builtin(__builtin_amdgcn_permlane32_swap)
    u32x2v r = __builtin_amdgcn_permlane32_swap(
        __builtin_bit_cast(unsigned, x), __builtin_bit_cast(unsigned, x), false, false);
    return __builtin_bit_cast(float, hi32 ? r[0] : r[1]);
#else
    return __shfl_xor(x, 32, 64);
#endif
}

// ===================== one-sided Jacobi eig, one wave per block =====================
// XOR pairing (q = j^m, m=1..63): perfect matching each round, all pairs per sweep.
// Incremental column-norm tracking (exact refresh at each sweep start).
// NOTE: 64-thread blocks, no multi-wave — the (256,3) multi-wave config broke
// the graph-replay determinism check in round 2; this config replay-passed.
//
// Pipe-balance rewrite: the kernel was DS-pipe-bound (32 blk/CU x 32.8k bpermute
// x ~7cyc = 7.3M cyc/CU ~= the measured 3.19ms). Exchanges for m in [1,39] now go
// through the VALU pipe (DPP + permlane swaps, bit-exact data movement); m in
// [40,63] stay on ds_bpermute. DS load drops ~60%, VALU picks up the rest, the
// two pipes overlap across ~12 resident waves. __launch_bounds__(64,3) gives the
// RA ~170 regs so a[64]+bb[64] live in arch VGPRs (no accvgpr spill moves).
__global__ __launch_bounds__(64, 3) void k_eig(const float* __restrict__ X, f16* __restrict__ U,
                                               f16* __restrict__ UT, float2* __restrict__ lam) {
    int b = blockIdx.x;
    int j = threadIdx.x;                 // lane = my column
    const float* Xb = X + (size_t)b * 4096;
    float a[64];
    #pragma unroll
    for (int i = 0; i < 64; ++i) a[i] = Xb[i * 64 + j];   // coalesced per i
    const bool odd16 = (j & 16) != 0;
    const bool hi32  = (j & 32) != 0;

    #pragma unroll 1
    for (int sweep = 0; sweep < SWEEPS; ++sweep) {
        float n2 = 0.0f;                  // exact norm refresh each sweep
        #pragma unroll
        for (int i = 0; i < 64; ++i) n2 = fmaf(a[i], a[i], n2);
        #pragma unroll 1
        for (int m = 1; m < 64; ++m) {
            int q = j ^ m;
            int q4 = q << 2;
            float nq = __builtin_bit_cast(float,
                __builtin_amdgcn_ds_bpermute(q4, __builtin_bit_cast(int, n2)));
            float bb[64];
            if (m >= 40) {
                // DS-pipe path (expensive-to-DPP masks)
                #pragma unroll
                for (int i = 0; i < 64; ++i)
                    bb[i] = __builtin_bit_cast(float,
                        __builtin_amdgcn_ds_bpermute(q4, __builtin_bit_cast(int, a[i])));
            } else {
                // VALU-pipe path: compose xor m from DPP / permlane primitives.
                // All branches are wave-uniform (m is the loop var).
                const int low = m & 7;
                if (low == 7) {
                    #pragma unroll
                    for (int i = 0; i < 64; ++i) bb[i] = dppf<0x141>(a[i]);
                } else if (low >= 4) {
                    #pragma unroll
                    for (int i = 0; i < 64; ++i) bb[i] = dppf<0x141>(a[i]);   // xor7
                    const int ql = low ^ 7;                                    // xor(ql) -> net xor(low)
                    if (ql == 1) {
                        #pragma unroll
                        for (int i = 0; i < 64; ++i) bb[i] = dppf<0xB1>(bb[i]);
                    } else if (ql == 2) {
                        #pragma unroll
                        for (int i = 0; i < 64; ++i) bb[i] = dppf<0x4E>(bb[i]);
                    } else {
                        #pragma unroll
                        for (int i = 0; i < 64; ++i) bb[i] = dppf<0x1B>(bb[i]);
                    }
                } else if (low == 1) {
                    #pragma unroll
                    for (int i = 0; i < 64; ++i) bb[i] = dppf<0xB1>(a[i]);
                } else if (low == 2) {
                    #pragma unroll
                    for (int i = 0; i < 64; ++i) bb[i] = dppf<0x4E>(a[i]);
                } else if (low == 3) {
                    #pragma unroll
                    for (int i = 0; i < 64; ++i) bb[i] = dppf<0x1B>(a[i]);
                } else {
                    // low == 0 (m in {8,16,24,32}): plain copy feeds the later stages
                    #pragma unroll
                    for (int i = 0; i < 64; ++i) bb[i] = a[i];
                }
                if (m & 8) {
                    #pragma unroll
                    for (int i = 0; i < 64; ++i) bb[i] = dppf<0x128>(bb[i]);  // xor8
                }
                if (m & 16) {
                    #pragma unroll
                    for (int i = 0; i < 64; ++i) bb[i] = pl16(bb[i], odd16);  // xor16
                }
                if (m & 32) {
                    #pragma unroll
                    for (int i = 0; i < 64; ++i) bb[i] = pl32(bb[i], hi32);   // xor32
                }
            }
            float dab = 0.0f;
            #pragma unroll
            for (int i = 0; i < 64; ++i) dab = fmaf(a[i], bb[i], dab);
            bool lower = j < q;
            float alpha = lower ? n2 : nq;
            float beta  = lower ? nq : n2;
            float c = 1.0f, s = 0.0f;
            if (dab * dab > 1e-26f * alpha * beta) {
                float zeta = (beta - alpha) / (2.0f * dab);
                float t = copysignf(1.0f, zeta) / (fabsf(zeta) + sqrtf(1.0f + zeta * zeta));
                c = rsqrtf(1.0f + t * t);
                s = t * c;
            }
            float se = lower ? -s : s;
            #pragma unroll
            for (int i = 0; i < 64; ++i) a[i] = fmaf(se, bb[i], c * a[i]);
            n2 = c * c * n2 + 2.0f * c * se * dab + se * se * nq;
        }
    }
    // columns now = lambda_j * u_j ; exact final norms
    float n2 = 0.0f;
    #pragma unroll
    for (int i = 0; i < 64; ++i) n2 = fmaf(a[i], a[i], n2);
    n2 = fmaxf(n2, 1e-30f);
    float lamv = sqrtf(n2);
    float inv = 1.0f / lamv;
    float logl = 0.5f * logf(n2);
    lam[(size_t)b * 64 + j] = make_float2(lamv, logl);
    f16* Ub = U + (size_t)b * 4096;
    f16* UTb = UT + (size_t)b * 4096;
    #pragma unroll
    for (int i = 0; i < 64; ++i) Ub[i * 64 + j] = (f16)(a[i] * inv);   // coalesced row writes
    #pragma unroll
    for (int i = 0; i < 64; i += 2) {                                   // my UT row, packed pairs
        f16x2v pv; pv[0] = (f16)(a[i] * inv); pv[1] = (f16)(a[i + 1] * inv);
        *(f16x2v*)(UTb + (size_t)j * 64 + i) = pv;
    }
}

// ===================== per-iteration mean prep (series for mean^{+-1/2}) =====================
__global__ __launch_bounds__(256) void k_prep(const float* __restrict__ mean, f16* __restrict__ d16,
                                              float* __restrict__ C12, float* __restrict__ state) {
    __shared__ float buf[3 * 4096];
    __shared__ float red[256];
    float *BA = buf, *BB = buf + 4096, *BC = buf + 8192;
    int tid = threadIdx.x;
    float tr = 0.0f;
    for (int idx = tid; idx < 4096; idx += 256) {
        float v = mean[idx]; BA[idx] = v;
        if (idx % 65 == 0) tr += v;
    }
    tr = bred256(tr, red);
    float g = tr / 64.0f, invg = 1.0f / g;
    for (int idx = tid; idx < 4096; idx += 256)
        BA[idx] = BA[idx] * invg - ((idx % 65 == 0) ? 1.0f : 0.0f);      // eps
    g64(BA, BA, BB, 1.0f, false);                                        // eps^2
    // d = -1/2 e + 3/8 e^2 - 5/16 e^3 + 35/128 e^4   (from (1+x)^{-1/2})
    for (int idx = tid; idx < 4096; idx += 256) BC[idx] = -0.5f * BA[idx] + 0.375f * BB[idx];
    g64(BB, BA, BC, -0.3125f, true);
    g64(BB, BB, BC, 0.2734375f, true);
    for (int idx = tid; idx < 4096; idx += 256) d16[idx] = (f16)BC[idx];
    __syncthreads();
    // C12 = sqrt(g) * (I + 1/2 e - 1/8 e^2 + 1/16 e^3 - 5/128 e^4)
    for (int idx = tid; idx < 4096; idx += 256)
        BC[idx] = ((idx % 65 == 0) ? 1.0f : 0.0f) + 0.5f * BA[idx] - 0.125f * BB[idx];
    g64(BB, BA, BC, 0.0625f, true);
    g64(BB, BB, BC, -0.0390625f, true);
    float sg = sqrtf(g);
    for (int idx = tid; idx < 4096; idx += 256) C12[idx] = sg * BC[idx];
    if (tid == 0) state[2] = -0.5f * logf(g);    // lw0 = log(gamma^{-1/2})
}

// ===================== MFMA wave-GEMM utilities (64x64x64, f16 in, fp32 acc) =====================
// computes C[m][n] += sum_k As[m,k]*Bs[n,k]  (i.e. A * B_rows^T)
__device__ __forceinline__ void wave_gemm(const f16* As, const f16* Bs, f32x4v C[4][4], bool zero) {
    const int lane = threadIdx.x & 63;
    const int cl = lane & 15, qd = lane >> 4;
    if (zero) {
        #pragma unroll
        for (int a = 0; a < 4; ++a)
            #pragma unroll
            for (int c = 0; c < 4; ++c) C[a][c] = f32x4v{0.f, 0.f, 0.f, 0.f};
    }
    #pragma unroll
    for (int ks = 0; ks < 2; ++ks) {
        f16x8v af[4], bf[4];
        #pragma unroll
        for (int t = 0; t < 4; ++t) {
            af[t] = *(const f16x8v*)&As[(16 * t + cl) * LDP + 32 * ks + qd * 8];
            bf[t] = *(const f16x8v*)&Bs[(16 * t + cl) * LDP + 32 * ks + qd * 8];
        }
        #pragma unroll
        for (int tm = 0; tm < 4; ++tm)
            #pragma unroll
            for (int tn = 0; tn < 4; ++tn)
                C[tm][tn] = __builtin_amdgcn_mfma_f32_16x16x32_f16(af[tm], bf[tn], C[tm][tn], 0, 0, 0);
    }
}

// store C-fragments column-major (contiguous b64) -> buffer holds (result)^T row-major
__device__ __forceinline__ void store_cm(f16* Ws, const f32x4v C[4][4]) {
    const int lane = threadIdx.x & 63;
    const int cl = lane & 15, qd = lane >> 4;
    #pragma unroll
    for (int tm = 0; tm < 4; ++tm)
        #pragma unroll
        for (int tn = 0; tn < 4; ++tn) {
            int R0 = 16 * tm + qd * 4, Cc = 16 * tn + cl;
            f16x4v p;
            p[0] = (f16)C[tm][tn][0]; p[1] = (f16)C[tm][tn][1];
            p[2] = (f16)C[tm][tn][2]; p[3] = (f16)C[tm][tn][3];
            *(f16x4v*)&Ws[Cc * LDP + R0] = p;
        }
}

// store with per-R scale (used to fold Lambda^{1/2} into the transpose store)
__device__ __forceinline__ void store_cm_s(f16* Ws, const f32x4v C[4][4], const float2 lrow[4][4]) {
    const int lane = threadIdx.x & 63;
    const int cl = lane & 15, qd = lane >> 4;
    #pragma unroll
    for (int tm = 0; tm < 4; ++tm)
        #pragma unroll
        for (int tn = 0; tn < 4; ++tn) {
            int R0 = 16 * tm + qd * 4, Cc = 16 * tn + cl;
            f16x4v p;
            #pragma unroll
            for (int i = 0; i < 4; ++i) p[i] = (f16)(C[tm][tn][i] * sqrtf(lrow[tm][i].x));
            *(f16x4v*)&Ws[Cc * LDP + R0] = p;
        }
}

// ===================== per-iteration batch kernel: J partials =====================
// M_b = w0^2 (I+d) X_b (I+d);  in U-basis: Lam + delta, delta = (la+lc)*dt + (dt Lam dt)
// with dt = U^T d U.  L_offdiag = dd(la,lc)*delta, L_diag = log(la) + log1p(delta_ii/la).
// J_b(no-scalar) = U L U^T.  Accumulate over 8 b's per wave.
__global__ __launch_bounds__(64) void k_batch(const f16* __restrict__ U, const f16* __restrict__ UT,
                                              const float2* __restrict__ lam, const f16* __restrict__ dmat,
                                              float* __restrict__ Jpart) {
    __shared__ __align__(16) f16 sD[64 * LDP];
    __shared__ __align__(16) f16 sU[64 * LDP];
    __shared__ __align__(16) f16 sUT[64 * LDP];
    __shared__ __align__(16) f16 sW[64 * LDP];
    const int lane = threadIdx.x;
    const int cl = lane & 15, qd = lane >> 4;

    #pragma unroll
    for (int t = 0; t < 8; ++t) {
        int k = t * 64 + lane;
        int row = k >> 3, off = (k & 7) << 3;
        *(f16x8v*)&sD[row * LDP + off] = *(const f16x8v*)(dmat + ((size_t)k << 3));
    }
    __syncthreads();

    f32x4v acc[4][4];
    #pragma unroll
    for (int a = 0; a < 4; ++a)
        #pragma unroll
        for (int c = 0; c < 4; ++c) acc[a][c] = f32x4v{0.f, 0.f, 0.f, 0.f};

    for (int bi = 0; bi < 8; ++bi) {
        int b = blockIdx.x * 8 + bi;
        const f16* Ub = U + (size_t)b * 4096;
        const f16* UTb = UT + (size_t)b * 4096;
        #pragma unroll
        for (int t = 0; t < 8; ++t) {
            int k = t * 64 + lane;
            int row = k >> 3, off = (k & 7) << 3;
            *(f16x8v*)&sU[row * LDP + off]  = *(const f16x8v*)(Ub + ((size_t)k << 3));
            *(f16x8v*)&sUT[row * LDP + off] = *(const f16x8v*)(UTb + ((size_t)k << 3));
        }
        const float2* lb = lam + (size_t)b * 64;
        float2 lcol[4], lrow[4][4];
        #pragma unroll
        for (int tn = 0; tn < 4; ++tn) lcol[tn] = lb[16 * tn + cl];
        #pragma unroll
        for (int tm = 0; tm < 4; ++tm)
            #pragma unroll
            for (int i = 0; i < 4; ++i) lrow[tm][i] = lb[16 * tm + qd * 4 + i];
        __syncthreads();

        f32x4v C1[4][4];
        wave_gemm(sD, sUT, C1, true);      // d*U
        __syncthreads();
        store_cm(sW, C1);                  // sW = (dU)^T = U^T d  (row-major)
        __syncthreads();
        f32x4v C2[4][4];
        wave_gemm(sW, sUT, C2, true);      // dt = U^T d U  (symmetric)
        __syncthreads();
        store_cm_s(sW, C2, lrow);          // sW = (Lam^{1/2} dt)^T = dt Lam^{1/2}  (row-major)
        __syncthreads();
        f32x4v C3[4][4];
        wave_gemm(sW, sW, C3, true);       // P = dt Lam dt
        // L = logLam*I + dd o delta,  delta = (la+lc)*dt + P ; exact diagonal via log1p
        #pragma unroll
        for (int tm = 0; tm < 4; ++tm)
            #pragma unroll
            for (int tn = 0; tn < 4; ++tn)
                #pragma unroll
                for (int i = 0; i < 4; ++i) {
                    float la = lrow[tm][i].x, lla = lrow[tm][i].y;
                    float lc = lcol[tn].x,  llc = lcol[tn].y;
                    float delta = (la + lc) * C2[tm][tn][i] + C3[tm][tn][i];
                    int R = 16 * tm + qd * 4 + i, Cc = 16 * tn + cl;
                    float Lv;
                    if (R == Cc) {
                        Lv = lla + log1pf(fmaxf(delta / la, -0.9999f));
                    } else {
                        float u = la - lc;
                        float dd = (fabsf(u) > 1e-3f * (la + lc)) ? (lla - llc) / u : 2.0f / (la + lc);
                        Lv = dd * delta;
                    }
                    C3[tm][tn][i] = Lv;
                }
        __syncthreads();
        store_cm(sW, C3);                  // L (symmetric) row-major
        __syncthreads();
        f32x4v C4[4][4];
        wave_gemm(sW, sU, C4, true);       // L*U^T
        __syncthreads();
        store_cm(sW, C4);                  // sW = (L U^T)^T = U L (row-major)
        __syncthreads();
        wave_gemm(sW, sU, acc, false);     // += (U L)*U^T
        __syncthreads();
    }
    float* Jp = Jpart + (size_t)blockIdx.x * 4096;
    #pragma unroll
    for (int tm = 0; tm < 4; ++tm)
        #pragma unroll
        for (int tn = 0; tn < 4; ++tn)
            #pragma unroll
            for (int i = 0; i < 4; ++i) {
                int R = 16 * tm + qd * 4 + i, Cc = 16 * tn + cl;
                Jp[R * 64 + Cc] = acc[tm][tn][i];
            }
}

__global__ __launch_bounds__(256) void k_jred(const float* __restrict__ Jpart, float* __restrict__ Jsum) {
    int e = blockIdx.x * 256 + threadIdx.x;
    float s = 0.0f;
    for (int p = 0; p < 1024; ++p) s += Jpart[(size_t)p * 4096 + e];
    Jsum[e] = s;
}

// ===================== J finalize + exp + mean update + schedule =====================
__global__ __launch_bounds__(256) void k_update(const float* __restrict__ Jsum, const float* __restrict__ C12g,
                                                float* __restrict__ meang, float* __restrict__ state) {
    __shared__ float buf[3 * 4096];
    __shared__ float red[256];
    float *BA = buf, *BB = buf + 4096, *BC = buf + 8192;
    int tid = threadIdx.x;
    float lw0 = state[2];
    float nu = state[0], tau = state[1];
    float c2 = 0.0f, trv = 0.0f;
    for (int idx = tid; idx < 4096; idx += 256) {
        float v = Jsum[idx] * (1.0f / 8192.0f) + ((idx % 65 == 0) ? 2.0f * lw0 : 0.0f);
        BA[idx] = v;
        c2 += v * v;
        if (idx % 65 == 0) trv += v;
    }
    c2 = bred256(c2, red);
    trv = bred256(trv, red);
    float crit = sqrtf(c2);
    float cc = trv / 64.0f;
    float h = nu * crit;
    // G = nu*(J - c I); exp(nu J) = e^{nu c} * (I + G + G^2/2 + G^3/6 + G^4/24)
    for (int idx = tid; idx < 4096; idx += 256)
        BA[idx] = nu * (BA[idx] - ((idx % 65 == 0) ? cc : 0.0f));
    g64(BA, BA, BB, 1.0f, false);                                   // G^2
    for (int idx = tid; idx < 4096; idx += 256)
        BC[idx] = ((idx % 65 == 0) ? 1.0f : 0.0f) + BA[idx] + 0.5f * BB[idx];
    g64(BB, BA, BC, 1.0f / 6.0f, true);                             // + G^3/6
    g64(BB, BB, BC, 1.0f / 24.0f, true);                            // + G^4/24
    float sc = expf(nu * cc);
    for (int idx = tid; idx < 4096; idx += 256) BC[idx] *= sc;      // E = exp(nu J)
    __syncthreads();
    for (int idx = tid; idx < 4096; idx += 256) BA[idx] = C12g[idx];
    g64(BA, BC, BB, 1.0f, false);                                   // T = C12 * E
    g64(BB, BA, BC, 1.0f, false);                                   // mean' = T * C12
    for (int idx = tid; idx < 4096; idx += 256) meang[idx] = BC[idx];
    if (tid == 0) {
        if (h < tau) { state[0] = 0.95f * nu; state[1] = h; }
        else         { state[0] = 0.5f * nu; }
    }
}

// ===================== final: P = sqrt(bias) * mean^{-1/2} =====================
__global__ __launch_bounds__(256) void k_final_prep(const float* __restrict__ mean, const float* __restrict__ S,
                                                    f16* __restrict__ P16) {
    __shared__ float buf[3 * 4096];
    __shared__ float red[256];
    float *BA = buf, *BB = buf + 4096, *BC = buf + 8192;
    int tid = threadIdx.x;
    float tr = 0.0f;
    for (int idx = tid; idx < 4096; idx += 256) {
        float v = mean[idx]; BA[idx] = v;
        if (idx % 65 == 0) tr += v;
    }
    tr = bred256(tr, red);
    float g = tr / 64.0f, invg = 1.0f / g;
    for (int idx = tid; idx < 4096; idx += 256)
        BA[idx] = BA[idx] * invg - ((idx % 65 == 0) ? 1.0f : 0.0f);
    g64(BA, BA, BB, 1.0f, false);
    for (int idx = tid; idx < 4096; idx += 256)
        BC[idx] = ((idx % 65 == 0) ? 1.0f : 0.0f) - 0.5f * BA[idx] + 0.375f * BB[idx];
    g64(BB, BA, BC, -0.3125f, true);
    g64(BB, BB, BC, 0.2734375f, true);       // BC = (I+eps)^{-1/2}
    float w0 = rsqrtf(g);
    g64(S, BC, BA, w0, false);               // P = w0 * S * BC  (S read from global)
    for (int idx = tid; idx < 4096; idx += 256) P16[idx] = (f16)BA[idx];
}

// ===================== output: Y_b = P X_b P^T =====================
__global__ __launch_bounds__(64) void k_out(const float* __restrict__ X, const f16* __restrict__ P16,
                                            float* __restrict__ out) {
    __shared__ __align__(16) f16 sP[64 * LDP];
    __shared__ __align__(16) f16 sX[64 * LDP];
    __shared__ __align__(16) f16 sW[64 * LDP];
    const int lane = threadIdx.x;
    const int cl = lane & 15, qd = lane >> 4;
    #pragma unroll
    for (int t = 0; t < 8; ++t) {
        int k = t * 64 + lane;
        int row = k >> 3, off = (k & 7) << 3;
        *(f16x8v*)&sP[row * LDP + off] = *(const f16x8v*)(P16 + ((size_t)k << 3));
    }
    __syncthreads();
    for (int bi = 0; bi < 4; ++bi) {
        int b = blockIdx.x * 4 + bi;
        const float* Xb = X + (size_t)b * 4096;
        #pragma unroll
        for (int t = 0; t < 16; ++t) {
            int k = t * 64 + lane;               // float4 chunk
            float4 v = ((const float4*)Xb)[k];
            int row = k >> 4, off = (k & 15) << 2;
            f16x4v h; h[0] = (f16)v.x; h[1] = (f16)v.y; h[2] = (f16)v.z; h[3] = (f16)v.w;
            *(f16x4v*)&sX[row * LDP + off] = h;
        }
        __syncthreads();
        f32x4v C1[4][4];
        wave_gemm(sX, sP, C1, true);          // X * P^T (X symmetric)
        __syncthreads();
        store_cm(sW, C1);                      // sW = (X P^T)^T = P X
        __syncthreads();
        f32x4v C2[4][4];
        wave_gemm(sW, sP, C2, true);           // (P X) * P^T = Y
        float* ob = out + (size_t)b * 4096;
        #pragma unroll
        for (int tm = 0; tm < 4; ++tm)
            #pragma unroll
            for (int tn = 0; tn < 4; ++tn)
                #pragma unroll
                for (int i = 0; i < 4; ++i) {
                    int R = 16 * tm + qd * 4 + i, Cc = 16 * tn + cl;
                    ob[R * 64 + Cc] = C2[tm][tn][i];
                }
        __syncthreads();
    }
}

// ===================== host =====================
extern "C" void kernel_launch(void* const* d_in, const int* in_sizes, int n_in,
                              void* d_out, int out_size, void* d_ws, size_t ws_size,
                              hipStream_t stream) {
    const float* X    = (const float*)d_in[0];
    const float* bias = (const float*)d_in[1];
    float* out = (float*)d_out;
    uint8_t* w = (uint8_t*)d_ws;

    f16*    U     = (f16*)(w + OFF_U);
    f16*    UT    = (f16*)(w + OFF_UT);
    float2* lam   = (float2*)(w + OFF_LAM);
    float*  mpart = (float*)(w + OFF_MPART);
    float*  Jpart = (float*)(w + OFF_JPART);
    float*  mean  = (float*)(w + OFF_MEAN);
    float*  C12   = (float*)(w + OFF_C12);
    float*  Jsum  = (float*)(w + OFF_JSUM);
    float*  S     = (float*)(w + OFF_S);
    f16*    P16   = (f16*)(w + OFF_P16);
    f16*    d16   = (f16*)(w + OFF_D16);
    float*  state = (float*)(w + OFF_STATE);

    k_mean_part<<<64, 256, 0, stream>>>(X, mpart);
    k_mean_fin<<<16, 256, 0, stream>>>(mpart, mean);
    k_init<<<1, 64, 0, stream>>>(state);
    k_bias_sqrt<<<1, 256, 0, stream>>>(bias, S);
    k_eig<<<8192, 64, 0, stream>>>(X, U, UT, lam);
    for (int it = 0; it < 5; ++it) {
        k_prep<<<1, 256, 0, stream>>>(mean, d16, C12, state);
        k_batch<<<1024, 64, 0, stream>>>(U, UT, lam, d16, Jpart);
        k_jred<<<16, 256, 0, stream>>>(Jpart, Jsum);
        k_update<<<1, 256, 0, stream>>>(Jsum, C12, mean, state);
    }
    k_final_prep<<<1, 256, 0, stream>>>(mean, S, P16);
    k_out<<<2048, 64, 0, stream>>>(X, P16, out);
}

// Round 5
// 3989.285 us; speedup vs baseline: 1.2979x; 1.2979x over previous
//
#include <hip/hip_runtime.h>
#include <cfloat>
#include <cstdint>
#include <cstddef>

typedef _Float16 f16;
typedef _Float16 f16x2v __attribute__((ext_vector_type(2)));
typedef _Float16 f16x4v __attribute__((ext_vector_type(4)));
typedef _Float16 f16x8v __attribute__((ext_vector_type(8)));
typedef float    f32x4v __attribute__((ext_vector_type(4)));

#define LDP 72          // padded f16 row stride (b128-aligned, breaks bank conflicts)
#define SWEEPS_F16 6    // packed-f16 exchange sweeps (fast)
#define SWEEPS_F32 2    // exact f32 cleanup sweeps (restore orthogonality)

// pack 2 f32 -> f16x2 via v_cvt_pkrtz (builtin returns __fp16x2; bit-cast to our type)
__device__ __forceinline__ f16x2v pkrtz(float a0, float a1) {
    return __builtin_bit_cast(f16x2v, __builtin_amdgcn_cvt_pkrtz(a0, a1));
}

// ===================== ws layout (bytes) =====================
#define OFF_U      ((size_t)0)                   // f16 [8192][64][64]  row-major (rows i, cols = eigvecs)
#define OFF_UT     (OFF_U + (size_t)67108864)    // f16 [8192][64][64]  U^T row-major
#define OFF_LAM    (OFF_UT + (size_t)67108864)   // float2 [8192][64]   (lambda, log lambda)
#define OFF_MPART  (OFF_LAM + (size_t)4194304)   // float [64][4096]
#define OFF_JPART  (OFF_MPART + (size_t)1048576) // float [1024][4096]
#define OFF_MEAN   (OFF_JPART + (size_t)16777216)
#define OFF_C12    (OFF_MEAN + 16384)
#define OFF_JSUM   (OFF_C12 + 16384)
#define OFF_S      (OFF_JSUM + 16384)            // sqrt(bias), fp32
#define OFF_P16    (OFF_S + 16384)               // P = S * isqrt(mean), f16 row-major
#define OFF_D16    (OFF_P16 + 8192)              // d matrix, f16 row-major
#define OFF_STATE  (OFF_D16 + 8192)              // [nu, tau, lw0, ...]
#define WS_NEEDED  (OFF_STATE + 256)

// ===================== small block helpers (256-thread kernels) =====================
__device__ __forceinline__ float bred256(float v, float* scr) {
    int tid = threadIdx.x;
    scr[tid] = v; __syncthreads();
    #pragma unroll
    for (int s = 128; s >= 1; s >>= 1) {
        if (tid < s) scr[tid] += scr[tid + s];
        __syncthreads();
    }
    float r = scr[0]; __syncthreads();
    return r;
}

// C = (accum ? C : 0) + scale * A*B   (64x64, generic pointers; has entry+exit barriers)
// Tiled: each thread computes 4 float4 output tiles; B read as b128 rows (was the
// serial-kernel hotspot: scalar version did ~2 ds_read_b32 per FMA, ~15us/call).
__device__ void g64(const float* A, const float* B, float* C, float scale, bool accum) {
    __syncthreads();
    int tid = threadIdx.x;
    #pragma unroll
    for (int it = 0; it < 4; ++it) {
        int t = (it << 8) + tid;            // tile id 0..1023
        int r = t >> 4, c0 = (t & 15) << 2; // row, col-start (x4)
        const float* Arow = A + (r << 6);
        f32x4v s = {0.f, 0.f, 0.f, 0.f};
        #pragma unroll 4
        for (int k = 0; k < 64; k += 4) {
            f32x4v av = *(const f32x4v*)(Arow + k);
            s += *(const f32x4v*)(B + ((k + 0) << 6) + c0) * av[0];
            s += *(const f32x4v*)(B + ((k + 1) << 6) + c0) * av[1];
            s += *(const f32x4v*)(B + ((k + 2) << 6) + c0) * av[2];
            s += *(const f32x4v*)(B + ((k + 3) << 6) + c0) * av[3];
        }
        int ci = (r << 6) + c0;
        f32x4v res = s * scale;
        if (accum) res += *(const f32x4v*)(C + ci);
        *(f32x4v*)(C + ci) = res;
    }
    __syncthreads();
}

// ===================== batch-mean reduction =====================
__global__ __launch_bounds__(256) void k_mean_part(const float* __restrict__ X, float* __restrict__ part) {
    int p = blockIdx.x, tid = threadIdx.x;
    float acc[16];
    #pragma unroll
    for (int t = 0; t < 16; ++t) acc[t] = 0.0f;
    const float* base = X + (size_t)p * 128 * 4096;
    for (int m = 0; m < 128; ++m) {
        const float* Xb = base + (size_t)m * 4096;
        #pragma unroll
        for (int t = 0; t < 16; ++t) acc[t] += Xb[t * 256 + tid];
    }
    #pragma unroll
    for (int t = 0; t < 16; ++t) part[(size_t)p * 4096 + t * 256 + tid] = acc[t];
}

__global__ __launch_bounds__(256) void k_mean_fin(const float* __restrict__ part, float* __restrict__ mean) {
    int e = blockIdx.x * 256 + threadIdx.x;
    float s = 0.0f;
    for (int p = 0; p < 64; ++p) s += part[(size_t)p * 4096 + e];
    mean[e] = s * (1.0f / 8192.0f);
}

__global__ __launch_bounds__(64) void k_init(float* __restrict__ state) {
    if (threadIdx.x == 0) { state[0] = 1.0f; state[1] = FLT_MAX; state[2] = 0.0f; }
}

// ===================== sqrt(bias) via coupled Newton-Schulz =====================
__global__ __launch_bounds__(256) void k_bias_sqrt(const float* __restrict__ bias, float* __restrict__ S) {
    __shared__ float buf[4 * 4096];   // exactly 64 KB
    float *B0 = buf, *B1 = buf + 4096, *B2 = buf + 8192, *B3 = buf + 12288;
    int tid = threadIdx.x;
    float p = 0.0f;
    for (int idx = tid; idx < 4096; idx += 256) { float v = bias[idx]; B0[idx] = v; p += v * v; }
    float fr2 = bred256(p, B1);       // B1 used as scratch before it becomes Z
    float g = sqrtf(fr2);             // gamma = ||bias||_F >= lambda_max
    float invg = 1.0f / g;
    for (int idx = tid; idx < 4096; idx += 256) {
        B0[idx] *= invg;
        B1[idx] = (idx % 65 == 0) ? 1.0f : 0.0f;
    }
    float *pY = B0, *pZ = B1, *pT = B2, *pS = B3;
    for (int it = 0; it < 10; ++it) {
        g64(pZ, pY, pT, -0.5f, false);                    // T = -0.5 Z Y
        for (int idx = tid; idx < 4096; idx += 256)
            if (idx % 65 == 0) pT[idx] += 1.5f;           // T = (3I - ZY)/2
        g64(pY, pT, pS, 1.0f, false);                     // newY
        float* oldY = pY; pY = pS; pS = oldY;
        g64(pT, pZ, pS, 1.0f, false);                     // newZ (into old Y)
        float* oldZ = pZ; pZ = pS; pS = oldZ;
    }
    float sg = sqrtf(g);
    __syncthreads();
    for (int idx = tid; idx < 4096; idx += 256) S[idx] = sg * pY[idx];
}

// ===================== one-sided Jacobi eig, one wave per block =====================
// XOR pairing (q = j^m, m=1..63): perfect matching each round, all pairs per sweep.
// DS-pipe-bound at 64 bpermute/round (7.2M cyc/CU ~= 3.0ms). Fix: exchange the
// partner column as PACKED f16x2 (cvt_pkrtz) -> 32 bpermutes/round. First
// SWEEPS_F16 sweeps packed, last SWEEPS_F32 sweeps exact f32 (one-sided Jacobi
// is self-correcting; final orthogonality set by the exact sweeps; U is stored
// f16 downstream anyway). Own column stays f32 throughout.
// NOTE: plain __launch_bounds__(64): round-1 showed that (64,3) + arch-VGPR-only
// ops makes the RA spill to scratch (1.7 GB writes) instead of using AGPRs.
__global__ __launch_bounds__(64) void k_eig(const float* __restrict__ X, f16* __restrict__ U,
                                            f16* __restrict__ UT, float2* __restrict__ lam) {
    int b = blockIdx.x;
    int j = threadIdx.x;                 // lane = my column
    const float* Xb = X + (size_t)b * 4096;
    float a[64];
    // X symmetric: column j == row j -> vectorized per-lane row load
    {
        const float4* Xr = (const float4*)(Xb + (size_t)j * 64);
        #pragma unroll
        for (int t = 0; t < 16; ++t) {
            float4 v = Xr[t];
            a[4 * t + 0] = v.x; a[4 * t + 1] = v.y;
            a[4 * t + 2] = v.z; a[4 * t + 3] = v.w;
        }
    }

    // ---- packed-f16 exchange sweeps ----
    #pragma unroll 1
    for (int sweep = 0; sweep < SWEEPS_F16; ++sweep) {
        float n2 = 0.0f;
        f16x2v ap[32];
        #pragma unroll
        for (int p = 0; p < 32; ++p) {
            float a0 = a[2 * p], a1 = a[2 * p + 1];
            n2 = fmaf(a0, a0, n2);
            n2 = fmaf(a1, a1, n2);
            ap[p] = pkrtz(a0, a1);
        }
        #pragma unroll 1
        for (int m = 1; m < 64; ++m) {
            int q = j ^ m;
            int q4 = q << 2;
            float nq = __builtin_bit_cast(float,
                __builtin_amdgcn_ds_bpermute(q4, __builtin_bit_cast(int, n2)));
            f16x2v bbp[32];
            #pragma unroll
            for (int p = 0; p < 32; ++p)
                bbp[p] = __builtin_bit_cast(f16x2v,
                    __builtin_amdgcn_ds_bpermute(q4, __builtin_bit_cast(int, ap[p])));
            float dab = 0.0f;
            #pragma unroll
            for (int p = 0; p < 32; ++p) {
                dab = fmaf((float)ap[p][0], (float)bbp[p][0], dab);
                dab = fmaf((float)ap[p][1], (float)bbp[p][1], dab);
            }
            bool lower = j < q;
            float alpha = lower ? n2 : nq;
            float beta  = lower ? nq : n2;
            float c = 1.0f, s = 0.0f;
            if (dab * dab > 1e-26f * alpha * beta) {
                float zeta = (beta - alpha) / (2.0f * dab);
                float t = copysignf(1.0f, zeta) / (fabsf(zeta) + sqrtf(1.0f + zeta * zeta));
                c = rsqrtf(1.0f + t * t);
                s = t * c;
            }
            float se = lower ? -s : s;
            #pragma unroll
            for (int p = 0; p < 32; ++p) {
                float b0 = (float)bbp[p][0], b1 = (float)bbp[p][1];
                float a0 = fmaf(se, b0, c * a[2 * p]);
                float a1 = fmaf(se, b1, c * a[2 * p + 1]);
                a[2 * p] = a0; a[2 * p + 1] = a1;
                ap[p] = pkrtz(a0, a1);    // keep packed copy current
            }
            n2 = c * c * n2 + 2.0f * c * se * dab + se * se * nq;
        }
    }

    // ---- exact f32 cleanup sweeps (baseline path) ----
    #pragma unroll 1
    for (int sweep = 0; sweep < SWEEPS_F32; ++sweep) {
        float n2 = 0.0f;
        #pragma unroll
        for (int i = 0; i < 64; ++i) n2 = fmaf(a[i], a[i], n2);
        #pragma unroll 1
        for (int m = 1; m < 64; ++m) {
            int q = j ^ m;
            int q4 = q << 2;
            float nq = __builtin_bit_cast(float,
                __builtin_amdgcn_ds_bpermute(q4, __builtin_bit_cast(int, n2)));
            float bb[64];
            float dab = 0.0f;
            #pragma unroll
            for (int i = 0; i < 64; ++i) {
                bb[i] = __builtin_bit_cast(float,
                    __builtin_amdgcn_ds_bpermute(q4, __builtin_bit_cast(int, a[i])));
                dab = fmaf(a[i], bb[i], dab);
            }
            bool lower = j < q;
            float alpha = lower ? n2 : nq;
            float beta  = lower ? nq : n2;
            float c = 1.0f, s = 0.0f;
            if (dab * dab > 1e-26f * alpha * beta) {
                float zeta = (beta - alpha) / (2.0f * dab);
                float t = copysignf(1.0f, zeta) / (fabsf(zeta) + sqrtf(1.0f + zeta * zeta));
                c = rsqrtf(1.0f + t * t);
                s = t * c;
            }
            float se = lower ? -s : s;
            #pragma unroll
            for (int i = 0; i < 64; ++i) a[i] = fmaf(se, bb[i], c * a[i]);
            n2 = c * c * n2 + 2.0f * c * se * dab + se * se * nq;
        }
    }

    // columns now = lambda_j * u_j ; exact final norms
    float n2 = 0.0f;
    #pragma unroll
    for (int i = 0; i < 64; ++i) n2 = fmaf(a[i], a[i], n2);
    n2 = fmaxf(n2, 1e-30f);
    float lamv = sqrtf(n2);
    float inv = 1.0f / lamv;
    float logl = 0.5f * logf(n2);
    lam[(size_t)b * 64 + j] = make_float2(lamv, logl);
    f16* Ub = U + (size_t)b * 4096;
    f16* UTb = UT + (size_t)b * 4096;
    #pragma unroll
    for (int i = 0; i < 64; ++i) Ub[i * 64 + j] = (f16)(a[i] * inv);   // coalesced row writes
    #pragma unroll
    for (int i = 0; i < 64; i += 2) {                                   // my UT row, packed pairs
        f16x2v pv; pv[0] = (f16)(a[i] * inv); pv[1] = (f16)(a[i + 1] * inv);
        *(f16x2v*)(UTb + (size_t)j * 64 + i) = pv;
    }
}

// ===================== mean prep core (series for mean^{+-1/2}) =====================
// M (LDS) holds the mean on entry; destroyed. W, O are LDS scratch.
__device__ void prep_core(float* M, float* W, float* O, float* red,
                          f16* d16, float* C12, float* state) {
    int tid = threadIdx.x;
    float tr = 0.0f;
    for (int idx = tid; idx < 4096; idx += 256)
        if (idx % 65 == 0) tr += M[idx];
    tr = bred256(tr, red);
    float g = tr / 64.0f, invg = 1.0f / g;
    for (int idx = tid; idx < 4096; idx += 256)
        M[idx] = M[idx] * invg - ((idx % 65 == 0) ? 1.0f : 0.0f);        // eps
    g64(M, M, W, 1.0f, false);                                           // eps^2
    // d = -1/2 e + 3/8 e^2 - 5/16 e^3 + 35/128 e^4   (from (1+x)^{-1/2})
    for (int idx = tid; idx < 4096; idx += 256) O[idx] = -0.5f * M[idx] + 0.375f * W[idx];
    g64(W, M, O, -0.3125f, true);
    g64(W, W, O, 0.2734375f, true);
    for (int idx = tid; idx < 4096; idx += 256) d16[idx] = (f16)O[idx];
    __syncthreads();
    // C12 = sqrt(g) * (I + 1/2 e - 1/8 e^2 + 1/16 e^3 - 5/128 e^4)
    for (int idx = tid; idx < 4096; idx += 256)
        O[idx] = ((idx % 65 == 0) ? 1.0f : 0.0f) + 0.5f * M[idx] - 0.125f * W[idx];
    g64(W, M, O, 0.0625f, true);
    g64(W, W, O, -0.0390625f, true);
    float sg = sqrtf(g);
    for (int idx = tid; idx < 4096; idx += 256) C12[idx] = sg * O[idx];
    if (tid == 0) state[2] = -0.5f * logf(g);    // lw0 = log(gamma^{-1/2})
}

__global__ __launch_bounds__(256) void k_prep(const float* __restrict__ mean, f16* __restrict__ d16,
                                              float* __restrict__ C12, float* __restrict__ state) {
    __shared__ float buf[3 * 4096];
    __shared__ float red[256];
    int tid = threadIdx.x;
    for (int idx = tid; idx < 4096; idx += 256) buf[idx] = mean[idx];
    prep_core(buf, buf + 4096, buf + 8192, red, d16, C12, state);
}

// ===================== MFMA wave-GEMM utilities (64x64x64, f16 in, fp32 acc) =====================
// computes C[m][n] += sum_k As[m,k]*Bs[n,k]  (i.e. A * B_rows^T)
__device__ __forceinline__ void wave_gemm(const f16* As, const f16* Bs, f32x4v C[4][4], bool zero) {
    const int lane = threadIdx.x & 63;
    const int cl = lane & 15, qd = lane >> 4;
    if (zero) {
        #pragma unroll
        for (int a = 0; a < 4; ++a)
            #pragma unroll
            for (int c = 0; c < 4; ++c) C[a][c] = f32x4v{0.f, 0.f, 0.f, 0.f};
    }
    #pragma unroll
    for (int ks = 0; ks < 2; ++ks) {
        f16x8v af[4], bf[4];
        #pragma unroll
        for (int t = 0; t < 4; ++t) {
            af[t] = *(const f16x8v*)&As[(16 * t + cl) * LDP + 32 * ks + qd * 8];
            bf[t] = *(const f16x8v*)&Bs[(16 * t + cl) * LDP + 32 * ks + qd * 8];
        }
        #pragma unroll
        for (int tm = 0; tm < 4; ++tm)
            #pragma unroll
            for (int tn = 0; tn < 4; ++tn)
                C[tm][tn] = __builtin_amdgcn_mfma_f32_16x16x32_f16(af[tm], bf[tn], C[tm][tn], 0, 0, 0);
    }
}

// store C-fragments column-major (contiguous b64) -> buffer holds (result)^T row-major
__device__ __forceinline__ void store_cm(f16* Ws, const f32x4v C[4][4]) {
    const int lane = threadIdx.x & 63;
    const int cl = lane & 15, qd = lane >> 4;
    #pragma unroll
    for (int tm = 0; tm < 4; ++tm)
        #pragma unroll
        for (int tn = 0; tn < 4; ++tn) {
            int R0 = 16 * tm + qd * 4, Cc = 16 * tn + cl;
            f16x4v p;
            p[0] = (f16)C[tm][tn][0]; p[1] = (f16)C[tm][tn][1];
            p[2] = (f16)C[tm][tn][2]; p[3] = (f16)C[tm][tn][3];
            *(f16x4v*)&Ws[Cc * LDP + R0] = p;
        }
}

// store with per-R scale (used to fold Lambda^{1/2} into the transpose store)
__device__ __forceinline__ void store_cm_s(f16* Ws, const f32x4v C[4][4], const float2 lrow[4][4]) {
    const int lane = threadIdx.x & 63;
    const int cl = lane & 15, qd = lane >> 4;
    #pragma unroll
    for (int tm = 0; tm < 4; ++tm)
        #pragma unroll
        for (int tn = 0; tn < 4; ++tn) {
            int R0 = 16 * tm + qd * 4, Cc = 16 * tn + cl;
            f16x4v p;
            #pragma unroll
            for (int i = 0; i < 4; ++i) p[i] = (f16)(C[tm][tn][i] * sqrtf(lrow[tm][i].x));
            *(f16x4v*)&Ws[Cc * LDP + R0] = p;
        }
}

// ===================== per-iteration batch kernel: J partials =====================
// M_b = w0^2 (I+d) X_b (I+d);  in U-basis: Lam + delta, delta = (la+lc)*dt + (dt Lam dt)
// with dt = U^T d U.  L_offdiag = dd(la,lc)*delta, L_diag = log(la) + log1p(delta_ii/la).
// J_b(no-scalar) = U L U^T.  Accumulate over 8 b's per wave.
__global__ __launch_bounds__(64) void k_batch(const f16* __restrict__ U, const f16* __restrict__ UT,
                                              const float2* __restrict__ lam, const f16* __restrict__ dmat,
                                              float* __restrict__ Jpart) {
    __shared__ __align__(16) f16 sD[64 * LDP];
    __shared__ __align__(16) f16 sU[64 * LDP];
    __shared__ __align__(16) f16 sUT[64 * LDP];
    __shared__ __align__(16) f16 sW[64 * LDP];
    const int lane = threadIdx.x;
    const int cl = lane & 15, qd = lane >> 4;

    #pragma unroll
    for (int t = 0; t < 8; ++t) {
        int k = t * 64 + lane;
        int row = k >> 3, off = (k & 7) << 3;
        *(f16x8v*)&sD[row * LDP + off] = *(const f16x8v*)(dmat + ((size_t)k << 3));
    }
    __syncthreads();

    f32x4v acc[4][4];
    #pragma unroll
    for (int a = 0; a < 4; ++a)
        #pragma unroll
        for (int c = 0; c < 4; ++c) acc[a][c] = f32x4v{0.f, 0.f, 0.f, 0.f};

    for (int bi = 0; bi < 8; ++bi) {
        int b = blockIdx.x * 8 + bi;
        const f16* Ub = U + (size_t)b * 4096;
        const f16* UTb = UT + (size_t)b * 4096;
        #pragma unroll
        for (int t = 0; t < 8; ++t) {
            int k = t * 64 + lane;
            int row = k >> 3, off = (k & 7) << 3;
            *(f16x8v*)&sU[row * LDP + off]  = *(const f16x8v*)(Ub + ((size_t)k << 3));
            *(f16x8v*)&sUT[row * LDP + off] = *(const f16x8v*)(UTb + ((size_t)k << 3));
        }
        const float2* lb = lam + (size_t)b * 64;
        float2 lcol[4], lrow[4][4];
        #pragma unroll
        for (int tn = 0; tn < 4; ++tn) lcol[tn] = lb[16 * tn + cl];
        #pragma unroll
        for (int tm = 0; tm < 4; ++tm)
            #pragma unroll
            for (int i = 0; i < 4; ++i) lrow[tm][i] = lb[16 * tm + qd * 4 + i];
        __syncthreads();

        f32x4v C1[4][4];
        wave_gemm(sD, sUT, C1, true);      // d*U
        __syncthreads();
        store_cm(sW, C1);                  // sW = (dU)^T = U^T d  (row-major)
        __syncthreads();
        f32x4v C2[4][4];
        wave_gemm(sW, sUT, C2, true);      // dt = U^T d U  (symmetric)
        __syncthreads();
        store_cm_s(sW, C2, lrow);          // sW = (Lam^{1/2} dt)^T = dt Lam^{1/2}  (row-major)
        __syncthreads();
        f32x4v C3[4][4];
        wave_gemm(sW, sW, C3, true);       // P = dt Lam dt
        // L = logLam*I + dd o delta,  delta = (la+lc)*dt + P ; exact diagonal via log1p
        #pragma unroll
        for (int tm = 0; tm < 4; ++tm)
            #pragma unroll
            for (int tn = 0; tn < 4; ++tn)
                #pragma unroll
                for (int i = 0; i < 4; ++i) {
                    float la = lrow[tm][i].x, lla = lrow[tm][i].y;
                    float lc = lcol[tn].x,  llc = lcol[tn].y;
                    float delta = (la + lc) * C2[tm][tn][i] + C3[tm][tn][i];
                    int R = 16 * tm + qd * 4 + i, Cc = 16 * tn + cl;
                    float Lv;
                    if (R == Cc) {
                        Lv = lla + log1pf(fmaxf(delta / la, -0.9999f));
                    } else {
                        float u = la - lc;
                        float dd = (fabsf(u) > 1e-3f * (la + lc)) ? (lla - llc) / u : 2.0f / (la + lc);
                        Lv = dd * delta;
                    }
                    C3[tm][tn][i] = Lv;
                }
        __syncthreads();
        store_cm(sW, C3);                  // L (symmetric) row-major
        __syncthreads();
        f32x4v C4[4][4];
        wave_gemm(sW, sU, C4, true);       // L*U^T
        __syncthreads();
        store_cm(sW, C4);                  // sW = (L U^T)^T = U L (row-major)
        __syncthreads();
        wave_gemm(sW, sU, acc, false);     // += (U L)*U^T
        __syncthreads();
    }
    float* Jp = Jpart + (size_t)blockIdx.x * 4096;
    #pragma unroll
    for (int tm = 0; tm < 4; ++tm)
        #pragma unroll
        for (int tn = 0; tn < 4; ++tn)
            #pragma unroll
            for (int i = 0; i < 4; ++i) {
                int R = 16 * tm + qd * 4 + i, Cc = 16 * tn + cl;
                Jp[R * 64 + Cc] = acc[tm][tn][i];
            }
}

__global__ __launch_bounds__(256) void k_jred(const float* __restrict__ Jpart, float* __restrict__ Jsum) {
    int e = blockIdx.x * 256 + threadIdx.x;
    float s = 0.0f;
    for (int p = 0; p < 1024; ++p) s += Jpart[(size_t)p * 4096 + e];
    Jsum[e] = s;
}

// ===================== fused: J finalize + exp + mean update + next-iter prep =====================
__global__ __launch_bounds__(256) void k_upstep(const float* __restrict__ Jsum, float* __restrict__ C12g,
                                                float* __restrict__ meang, float* __restrict__ state,
                                                f16* __restrict__ d16) {
    __shared__ float buf[3 * 4096];
    __shared__ float red[256];
    float *BA = buf, *BB = buf + 4096, *BC = buf + 8192;
    int tid = threadIdx.x;
    float lw0 = state[2];
    float nu = state[0], tau = state[1];
    float c2 = 0.0f, trv = 0.0f;
    for (int idx = tid; idx < 4096; idx += 256) {
        float v = Jsum[idx] * (1.0f / 8192.0f) + ((idx % 65 == 0) ? 2.0f * lw0 : 0.0f);
        BA[idx] = v;
        c2 += v * v;
        if (idx % 65 == 0) trv += v;
    }
    c2 = bred256(c2, red);
    trv = bred256(trv, red);
    float crit = sqrtf(c2);
    float cc = trv / 64.0f;
    float h = nu * crit;
    // G = nu*(J - c I); exp(nu J) = e^{nu c} * (I + G + G^2/2 + G^3/6 + G^4/24)
    for (int idx = tid; idx < 4096; idx += 256)
        BA[idx] = nu * (BA[idx] - ((idx % 65 == 0) ? cc : 0.0f));
    g64(BA, BA, BB, 1.0f, false);                                   // G^2
    for (int idx = tid; idx < 4096; idx += 256)
        BC[idx] = ((idx % 65 == 0) ? 1.0f : 0.0f) + BA[idx] + 0.5f * BB[idx];
    g64(BB, BA, BC, 1.0f / 6.0f, true);                             // + G^3/6
    g64(BB, BB, BC, 1.0f / 24.0f, true);                            // + G^4/24
    float sc = expf(nu * cc);
    for (int idx = tid; idx < 4096; idx += 256) BC[idx] *= sc;      // E = exp(nu J)
    __syncthreads();
    for (int idx = tid; idx < 4096; idx += 256) BA[idx] = C12g[idx];
    g64(BA, BC, BB, 1.0f, false);                                   // T = C12 * E
    g64(BB, BA, BC, 1.0f, false);                                   // mean' = T * C12
    for (int idx = tid; idx < 4096; idx += 256) meang[idx] = BC[idx];
    if (tid == 0) {
        if (h < tau) { state[0] = 0.95f * nu; state[1] = h; }
        else         { state[0] = 0.5f * nu; }
    }
    __syncthreads();
    // prep for the next iteration: consumes mean' in BC, overwrites BA/BB, writes d16 + new C12
    prep_core(BC, BA, BB, red, d16, C12g, state);
}

// ===================== final: P = sqrt(bias) * mean^{-1/2} =====================
__global__ __launch_bounds__(256) void k_final_prep(const float* __restrict__ mean, const float* __restrict__ S,
                                                    f16* __restrict__ P16) {
    __shared__ float buf[3 * 4096];
    __shared__ float red[256];
    float *BA = buf, *BB = buf + 4096, *BC = buf + 8192;
    int tid = threadIdx.x;
    float tr = 0.0f;
    for (int idx = tid; idx < 4096; idx += 256) {
        float v = mean[idx]; BA[idx] = v;
        if (idx % 65 == 0) tr += v;
    }
    tr = bred256(tr, red);
    float g = tr / 64.0f, invg = 1.0f / g;
    for (int idx = tid; idx < 4096; idx += 256)
        BA[idx] = BA[idx] * invg - ((idx % 65 == 0) ? 1.0f : 0.0f);
    g64(BA, BA, BB, 1.0f, false);
    for (int idx = tid; idx < 4096; idx += 256)
        BC[idx] = ((idx % 65 == 0) ? 1.0f : 0.0f) - 0.5f * BA[idx] + 0.375f * BB[idx];
    g64(BB, BA, BC, -0.3125f, true);
    g64(BB, BB, BC, 0.2734375f, true);       // BC = (I+eps)^{-1/2}
    float w0 = rsqrtf(g);
    g64(S, BC, BA, w0, false);               // P = w0 * S * BC  (S read from global)
    for (int idx = tid; idx < 4096; idx += 256) P16[idx] = (f16)BA[idx];
}

// ===================== output: Y_b = P X_b P^T =====================
__global__ __launch_bounds__(64) void k_out(const float* __restrict__ X, const f16* __restrict__ P16,
                                            float* __restrict__ out) {
    __shared__ __align__(16) f16 sP[64 * LDP];
    __shared__ __align__(16) f16 sX[64 * LDP];
    __shared__ __align__(16) f16 sW[64 * LDP];
    const int lane = threadIdx.x;
    const int cl = lane & 15, qd = lane >> 4;
    #pragma unroll
    for (int t = 0; t < 8; ++t) {
        int k = t * 64 + lane;
        int row = k >> 3, off = (k & 7) << 3;
        *(f16x8v*)&sP[row * LDP + off] = *(const f16x8v*)(P16 + ((size_t)k << 3));
    }
    __syncthreads();
    for (int bi = 0; bi < 4; ++bi) {
        int b = blockIdx.x * 4 + bi;
        const float* Xb = X + (size_t)b * 4096;
        #pragma unroll
        for (int t = 0; t < 16; ++t) {
            int k = t * 64 + lane;               // float4 chunk
            float4 v = ((const float4*)Xb)[k];
            int row = k >> 4, off = (k & 15) << 2;
            f16x4v h; h[0] = (f16)v.x; h[1] = (f16)v.y; h[2] = (f16)v.z; h[3] = (f16)v.w;
            *(f16x4v*)&sX[row * LDP + off] = h;
        }
        __syncthreads();
        f32x4v C1[4][4];
        wave_gemm(sX, sP, C1, true);          // X * P^T (X symmetric)
        __syncthreads();
        store_cm(sW, C1);                      // sW = (X P^T)^T = P X
        __syncthreads();
        f32x4v C2[4][4];
        wave_gemm(sW, sP, C2, true);           // (P X) * P^T = Y
        float* ob = out + (size_t)b * 4096;
        #pragma unroll
        for (int tm = 0; tm < 4; ++tm)
            #pragma unroll
            for (int tn = 0; tn < 4; ++tn)
                #pragma unroll
                for (int i = 0; i < 4; ++i) {
                    int R = 16 * tm + qd * 4 + i, Cc = 16 * tn + cl;
                    ob[R * 64 + Cc] = C2[tm][tn][i];
                }
        __syncthreads();
    }
}

// ===================== host =====================
extern "C" void kernel_launch(void* const* d_in, const int* in_sizes, int n_in,
                              void* d_out, int out_size, void* d_ws, size_t ws_size,
                              hipStream_t stream) {
    const float* X    = (const float*)d_in[0];
    const float* bias = (const float*)d_in[1];
    float* out = (float*)d_out;
    uint8_t* w = (uint8_t*)d_ws;

    f16*    U     = (f16*)(w + OFF_U);
    f16*    UT    = (f16*)(w + OFF_UT);
    float2* lam   = (float2*)(w + OFF_LAM);
    float*  mpart = (float*)(w + OFF_MPART);
    float*  Jpart = (float*)(w + OFF_JPART);
    float*  mean  = (float*)(w + OFF_MEAN);
    float*  C12   = (float*)(w + OFF_C12);
    float*  Jsum  = (float*)(w + OFF_JSUM);
    float*  S     = (float*)(w + OFF_S);
    f16*    P16   = (f16*)(w + OFF_P16);
    f16*    d16   = (f16*)(w + OFF_D16);
    float*  state = (float*)(w + OFF_STATE);

    k_mean_part<<<64, 256, 0, stream>>>(X, mpart);
    k_mean_fin<<<16, 256, 0, stream>>>(mpart, mean);
    k_init<<<1, 64, 0, stream>>>(state);
    k_bias_sqrt<<<1, 256, 0, stream>>>(bias, S);
    k_eig<<<8192, 64, 0, stream>>>(X, U, UT, lam);
    k_prep<<<1, 256, 0, stream>>>(mean, d16, C12, state);
    for (int it = 0; it < 5; ++it) {
        k_batch<<<1024, 64, 0, stream>>>(U, UT, lam, d16, Jpart);
        k_jred<<<16, 256, 0, stream>>>(Jpart, Jsum);
        k_upstep<<<1, 256, 0, stream>>>(Jsum, C12, mean, state, d16);
    }
    k_final_prep<<<1, 256, 0, stream>>>(mean, S, P16);
    k_out<<<2048, 64, 0, stream>>>(X, P16, out);
}

// Round 9
// 3932.125 us; speedup vs baseline: 1.3167x; 1.0145x over previous
//
#include <hip/hip_runtime.h>
#include <cfloat>
#include <cstdint>
#include <cstddef>

typedef _Float16 f16;
typedef _Float16 f16x2v __attribute__((ext_vector_type(2)));
typedef _Float16 f16x4v __attribute__((ext_vector_type(4)));
typedef _Float16 f16x8v __attribute__((ext_vector_type(8)));
typedef __fp16   h16x2v __attribute__((ext_vector_type(2)));   // builtin-native half2
typedef float    f32x4v __attribute__((ext_vector_type(4)));

#define LDP 72          // padded f16 row stride (b128-aligned, breaks bank conflicts)
#define SWEEPS_F16 6    // packed-f16 exchange sweeps (r7: 5 sweeps FAILED absmax 0.375 — keep 6)
#define SWEEPS_F32 2    // exact f32 cleanup sweeps (restore orthogonality)

// pack 2 f32 -> f16x2 via v_cvt_pkrtz (builtin returns __fp16x2; bit-cast to our type)
__device__ __forceinline__ f16x2v pkrtz(float a0, float a1) {
    return __builtin_bit_cast(f16x2v, __builtin_amdgcn_cvt_pkrtz(a0, a1));
}

// packed half2 dot-accumulate: dab += a.x*b.x + a.y*b.y  (v_dot2_f32_f16)
__device__ __forceinline__ float dot2acc(f16x2v a, f16x2v b, float acc) {
#if __has_builtin(__builtin_amdgcn_fdot2)
    return __builtin_amdgcn_fdot2(__builtin_bit_cast(h16x2v, a),
                                  __builtin_bit_cast(h16x2v, b), acc, false);
#else
    acc = fmaf((float)a[0], (float)b[0], acc);
    return fmaf((float)a[1], (float)b[1], acc);
#endif
}

// ===================== ws layout (bytes) =====================
#define OFF_U      ((size_t)0)                   // f16 [8192][64][64]  row-major (rows i, cols = eigvecs)
#define OFF_UT     (OFF_U + (size_t)67108864)    // f16 [8192][64][64]  U^T row-major
#define OFF_LAM    (OFF_UT + (size_t)67108864)   // float2 [8192][64]   (lambda, log lambda)
#define OFF_MPART  (OFF_LAM + (size_t)4194304)   // float [64][4096] (batch-mean partials; reused as Jsum quarters)
#define OFF_JPART  (OFF_MPART + (size_t)1048576) // float [1024][4096]
#define OFF_MEAN   (OFF_JPART + (size_t)16777216)
#define OFF_C12    (OFF_MEAN + 16384)
#define OFF_JSUM   (OFF_C12 + 16384)             // (unused; kept for layout stability)
#define OFF_S      (OFF_JSUM + 16384)            // sqrt(bias), fp32
#define OFF_P16    (OFF_S + 16384)               // P = S * isqrt(mean), f16 row-major
#define OFF_D16    (OFF_P16 + 8192)              // d matrix, f16 row-major
#define OFF_STATE  (OFF_D16 + 8192)              // [nu, tau, lw0, ...]
#define WS_NEEDED  (OFF_STATE + 256)

// ===================== small block helpers (256-thread kernels) =====================
__device__ __forceinline__ float bred256(float v, float* scr) {
    int tid = threadIdx.x;
    scr[tid] = v; __syncthreads();
    #pragma unroll
    for (int s = 128; s >= 1; s >>= 1) {
        if (tid < s) scr[tid] += scr[tid + s];
        __syncthreads();
    }
    float r = scr[0]; __syncthreads();
    return r;
}

// C = (accum ? C : 0) + scale * A*B   (64x64, generic pointers; has entry+exit barriers)
// Tiled: each thread computes 4 float4 output tiles; B read as b128 rows (was the
// serial-kernel hotspot: scalar version did ~2 ds_read_b32 per FMA, ~15us/call).
__device__ void g64(const float* A, const float* B, float* C, float scale, bool accum) {
    __syncthreads();
    int tid = threadIdx.x;
    #pragma unroll
    for (int it = 0; it < 4; ++it) {
        int t = (it << 8) + tid;            // tile id 0..1023
        int r = t >> 4, c0 = (t & 15) << 2; // row, col-start (x4)
        const float* Arow = A + (r << 6);
        f32x4v s = {0.f, 0.f, 0.f, 0.f};
        #pragma unroll 4
        for (int k = 0; k < 64; k += 4) {
            f32x4v av = *(const f32x4v*)(Arow + k);
            s += *(const f32x4v*)(B + ((k + 0) << 6) + c0) * av[0];
            s += *(const f32x4v*)(B + ((k + 1) << 6) + c0) * av[1];
            s += *(const f32x4v*)(B + ((k + 2) << 6) + c0) * av[2];
            s += *(const f32x4v*)(B + ((k + 3) << 6) + c0) * av[3];
        }
        int ci = (r << 6) + c0;
        f32x4v res = s * scale;
        if (accum) res += *(const f32x4v*)(C + ci);
        *(f32x4v*)(C + ci) = res;
    }
    __syncthreads();
}

// ===================== batch-mean reduction =====================
__global__ __launch_bounds__(256) void k_mean_part(const float* __restrict__ X, float* __restrict__ part) {
    int p = blockIdx.x, tid = threadIdx.x;
    float acc[16];
    #pragma unroll
    for (int t = 0; t < 16; ++t) acc[t] = 0.0f;
    const float* base = X + (size_t)p * 128 * 4096;
    for (int m = 0; m < 128; ++m) {
        const float* Xb = base + (size_t)m * 4096;
        #pragma unroll
        for (int t = 0; t < 16; ++t) acc[t] += Xb[t * 256 + tid];
    }
    #pragma unroll
    for (int t = 0; t < 16; ++t) part[(size_t)p * 4096 + t * 256 + tid] = acc[t];
}

__global__ __launch_bounds__(256) void k_mean_fin(const float* __restrict__ part, float* __restrict__ mean) {
    int e = blockIdx.x * 256 + threadIdx.x;
    float s = 0.0f;
    for (int p = 0; p < 64; ++p) s += part[(size_t)p * 4096 + e];
    mean[e] = s * (1.0f / 8192.0f);
}

__global__ __launch_bounds__(64) void k_init(float* __restrict__ state) {
    if (threadIdx.x == 0) { state[0] = 1.0f; state[1] = FLT_MAX; state[2] = 0.0f; }
}

// ===================== sqrt(bias) via coupled Newton-Schulz =====================
__global__ __launch_bounds__(256) void k_bias_sqrt(const float* __restrict__ bias, float* __restrict__ S) {
    __shared__ float buf[4 * 4096];   // exactly 64 KB
    float *B0 = buf, *B1 = buf + 4096, *B2 = buf + 8192, *B3 = buf + 12288;
    int tid = threadIdx.x;
    float p = 0.0f;
    for (int idx = tid; idx < 4096; idx += 256) { float v = bias[idx]; B0[idx] = v; p += v * v; }
    float fr2 = bred256(p, B1);       // B1 used as scratch before it becomes Z
    float g = sqrtf(fr2);             // gamma = ||bias||_F >= lambda_max
    float invg = 1.0f / g;
    for (int idx = tid; idx < 4096; idx += 256) {
        B0[idx] *= invg;
        B1[idx] = (idx % 65 == 0) ? 1.0f : 0.0f;
    }
    float *pY = B0, *pZ = B1, *pT = B2, *pS = B3;
    for (int it = 0; it < 10; ++it) {
        g64(pZ, pY, pT, -0.5f, false);                    // T = -0.5 Z Y
        for (int idx = tid; idx < 4096; idx += 256)
            if (idx % 65 == 0) pT[idx] += 1.5f;           // T = (3I - ZY)/2
        g64(pY, pT, pS, 1.0f, false);                     // newY
        float* oldY = pY; pY = pS; pS = oldY;
        g64(pT, pZ, pS, 1.0f, false);                     // newZ (into old Y)
        float* oldZ = pZ; pZ = pS; pS = oldZ;
    }
    float sg = sqrtf(g);
    __syncthreads();
    for (int idx = tid; idx < 4096; idx += 256) S[idx] = sg * pY[idx];
}

// ===================== one-sided Jacobi eig, one wave per block =====================
// XOR pairing (q = j^m, m=1..63): perfect matching each round, all pairs per sweep.
// r5 PMC: VALUBusy 81% + DS-model 1.93ms -> jointly DS+VALU bound. dab now via
// v_dot2_f32_f16 (kills ~128 cvt + 64 fma per round; bit-comparable accuracy).
// SWEEPS_F16 stays 6: r7 proved 5 packed sweeps fail absmax (0.375 > 0.26) —
// the 6th sweep is load-bearing, not idle.
// NOTE: plain __launch_bounds__(64): round-1 showed that (64,3) + arch-VGPR-only
// ops makes the RA spill to scratch (1.7 GB writes) instead of using AGPRs.
__global__ __launch_bounds__(64) void k_eig(const float* __restrict__ X, f16* __restrict__ U,
                                            f16* __restrict__ UT, float2* __restrict__ lam) {
    int b = blockIdx.x;
    int j = threadIdx.x;                 // lane = my column
    const float* Xb = X + (size_t)b * 4096;
    float a[64];
    // X symmetric: column j == row j -> vectorized per-lane row load
    {
        const float4* Xr = (const float4*)(Xb + (size_t)j * 64);
        #pragma unroll
        for (int t = 0; t < 16; ++t) {
            float4 v = Xr[t];
            a[4 * t + 0] = v.x; a[4 * t + 1] = v.y;
            a[4 * t + 2] = v.z; a[4 * t + 3] = v.w;
        }
    }

    // ---- packed-f16 exchange sweeps ----
    #pragma unroll 1
    for (int sweep = 0; sweep < SWEEPS_F16; ++sweep) {
        float n2 = 0.0f;
        f16x2v ap[32];
        #pragma unroll
        for (int p = 0; p < 32; ++p) {
            float a0 = a[2 * p], a1 = a[2 * p + 1];
            n2 = fmaf(a0, a0, n2);
            n2 = fmaf(a1, a1, n2);
            ap[p] = pkrtz(a0, a1);
        }
        #pragma unroll 1
        for (int m = 1; m < 64; ++m) {
            int q = j ^ m;
            int q4 = q << 2;
            float nq = __builtin_bit_cast(float,
                __builtin_amdgcn_ds_bpermute(q4, __builtin_bit_cast(int, n2)));
            f16x2v bbp[32];
            #pragma unroll
            for (int p = 0; p < 32; ++p)
                bbp[p] = __builtin_bit_cast(f16x2v,
                    __builtin_amdgcn_ds_bpermute(q4, __builtin_bit_cast(int, ap[p])));
            float dab = 0.0f;
            #pragma unroll
            for (int p = 0; p < 32; ++p)
                dab = dot2acc(ap[p], bbp[p], dab);     // v_dot2_f32_f16
            bool lower = j < q;
            float alpha = lower ? n2 : nq;
            float beta  = lower ? nq : n2;
            float c = 1.0f, s = 0.0f;
            if (dab * dab > 1e-26f * alpha * beta) {
                float zeta = (beta - alpha) / (2.0f * dab);
                float t = copysignf(1.0f, zeta) / (fabsf(zeta) + sqrtf(1.0f + zeta * zeta));
                c = rsqrtf(1.0f + t * t);
                s = t * c;
            }
            float se = lower ? -s : s;
            #pragma unroll
            for (int p = 0; p < 32; ++p) {
                float b0 = (float)bbp[p][0], b1 = (float)bbp[p][1];
                float a0 = fmaf(se, b0, c * a[2 * p]);
                float a1 = fmaf(se, b1, c * a[2 * p + 1]);
                a[2 * p] = a0; a[2 * p + 1] = a1;
                ap[p] = pkrtz(a0, a1);    // keep packed copy current
            }
            n2 = c * c * n2 + 2.0f * c * se * dab + se * se * nq;
        }
    }

    // ---- exact f32 cleanup sweeps (baseline path) ----
    #pragma unroll 1
    for (int sweep = 0; sweep < SWEEPS_F32; ++sweep) {
        float n2 = 0.0f;
        #pragma unroll
        for (int i = 0; i < 64; ++i) n2 = fmaf(a[i], a[i], n2);
        #pragma unroll 1
        for (int m = 1; m < 64; ++m) {
            int q = j ^ m;
            int q4 = q << 2;
            float nq = __builtin_bit_cast(float,
                __builtin_amdgcn_ds_bpermute(q4, __builtin_bit_cast(int, n2)));
            float bb[64];
            float dab = 0.0f;
            #pragma unroll
            for (int i = 0; i < 64; ++i) {
                bb[i] = __builtin_bit_cast(float,
                    __builtin_amdgcn_ds_bpermute(q4, __builtin_bit_cast(int, a[i])));
                dab = fmaf(a[i], bb[i], dab);
            }
            bool lower = j < q;
            float alpha = lower ? n2 : nq;
            float beta  = lower ? nq : n2;
            float c = 1.0f, s = 0.0f;
            if (dab * dab > 1e-26f * alpha * beta) {
                float zeta = (beta - alpha) / (2.0f * dab);
                float t = copysignf(1.0f, zeta) / (fabsf(zeta) + sqrtf(1.0f + zeta * zeta));
                c = rsqrtf(1.0f + t * t);
                s = t * c;
            }
            float se = lower ? -s : s;
            #pragma unroll
            for (int i = 0; i < 64; ++i) a[i] = fmaf(se, bb[i], c * a[i]);
            n2 = c * c * n2 + 2.0f * c * se * dab + se * se * nq;
        }
    }

    // columns now = lambda_j * u_j ; exact final norms
    float n2 = 0.0f;
    #pragma unroll
    for (int i = 0; i < 64; ++i) n2 = fmaf(a[i], a[i], n2);
    n2 = fmaxf(n2, 1e-30f);
    float lamv = sqrtf(n2);
    float inv = 1.0f / lamv;
    float logl = 0.5f * logf(n2);
    lam[(size_t)b * 64 + j] = make_float2(lamv, logl);
    f16* Ub = U + (size_t)b * 4096;
    f16* UTb = UT + (size_t)b * 4096;
    #pragma unroll
    for (int i = 0; i < 64; ++i) Ub[i * 64 + j] = (f16)(a[i] * inv);   // coalesced row writes
    #pragma unroll
    for (int i = 0; i < 64; i += 2) {                                   // my UT row, packed pairs
        f16x2v pv; pv[0] = (f16)(a[i] * inv); pv[1] = (f16)(a[i + 1] * inv);
        *(f16x2v*)(UTb + (size_t)j * 64 + i) = pv;
    }
}

// ===================== mean prep core (series for mean^{+-1/2}) =====================
// M (LDS) holds the mean on entry; destroyed. W, O are LDS scratch.
__device__ void prep_core(float* M, float* W, float* O, float* red,
                          f16* d16, float* C12, float* state) {
    int tid = threadIdx.x;
    float tr = 0.0f;
    for (int idx = tid; idx < 4096; idx += 256)
        if (idx % 65 == 0) tr += M[idx];
    tr = bred256(tr, red);
    float g = tr / 64.0f, invg = 1.0f / g;
    for (int idx = tid; idx < 4096; idx += 256)
        M[idx] = M[idx] * invg - ((idx % 65 == 0) ? 1.0f : 0.0f);        // eps
    g64(M, M, W, 1.0f, false);                                           // eps^2
    // d = -1/2 e + 3/8 e^2 - 5/16 e^3 + 35/128 e^4   (from (1+x)^{-1/2})
    for (int idx = tid; idx < 4096; idx += 256) O[idx] = -0.5f * M[idx] + 0.375f * W[idx];
    g64(W, M, O, -0.3125f, true);
    g64(W, W, O, 0.2734375f, true);
    for (int idx = tid; idx < 4096; idx += 256) d16[idx] = (f16)O[idx];
    __syncthreads();
    // C12 = sqrt(g) * (I + 1/2 e - 1/8 e^2 + 1/16 e^3 - 5/128 e^4)
    for (int idx = tid; idx < 4096; idx += 256)
        O[idx] = ((idx % 65 == 0) ? 1.0f : 0.0f) + 0.5f * M[idx] - 0.125f * W[idx];
    g64(W, M, O, 0.0625f, true);
    g64(W, W, O, -0.0390625f, true);
    float sg = sqrtf(g);
    for (int idx = tid; idx < 4096; idx += 256) C12[idx] = sg * O[idx];
    if (tid == 0) state[2] = -0.5f * logf(g);    // lw0 = log(gamma^{-1/2})
}

__global__ __launch_bounds__(256) void k_prep(const float* __restrict__ mean, f16* __restrict__ d16,
                                              float* __restrict__ C12, float* __restrict__ state) {
    __shared__ float buf[3 * 4096];
    __shared__ float red[256];
    int tid = threadIdx.x;
    for (int idx = tid; idx < 4096; idx += 256) buf[idx] = mean[idx];
    prep_core(buf, buf + 4096, buf + 8192, red, d16, C12, state);
}

// ===================== MFMA wave-GEMM utilities (64x64x64, f16 in, fp32 acc) =====================
// computes C[m][n] += sum_k As[m,k]*Bs[n,k]  (i.e. A * B_rows^T)
__device__ __forceinline__ void wave_gemm(const f16* As, const f16* Bs, f32x4v C[4][4], bool zero) {
    const int lane = threadIdx.x & 63;
    const int cl = lane & 15, qd = lane >> 4;
    if (zero) {
        #pragma unroll
        for (int a = 0; a < 4; ++a)
            #pragma unroll
            for (int c = 0; c < 4; ++c) C[a][c] = f32x4v{0.f, 0.f, 0.f, 0.f};
    }
    #pragma unroll
    for (int ks = 0; ks < 2; ++ks) {
        f16x8v af[4], bf[4];
        #pragma unroll
        for (int t = 0; t < 4; ++t) {
            af[t] = *(const f16x8v*)&As[(16 * t + cl) * LDP + 32 * ks + qd * 8];
            bf[t] = *(const f16x8v*)&Bs[(16 * t + cl) * LDP + 32 * ks + qd * 8];
        }
        #pragma unroll
        for (int tm = 0; tm < 4; ++tm)
            #pragma unroll
            for (int tn = 0; tn < 4; ++tn)
                C[tm][tn] = __builtin_amdgcn_mfma_f32_16x16x32_f16(af[tm], bf[tn], C[tm][tn], 0, 0, 0);
    }
}

// store C-fragments column-major (contiguous b64) -> buffer holds (result)^T row-major
__device__ __forceinline__ void store_cm(f16* Ws, const f32x4v C[4][4]) {
    const int lane = threadIdx.x & 63;
    const int cl = lane & 15, qd = lane >> 4;
    #pragma unroll
    for (int tm = 0; tm < 4; ++tm)
        #pragma unroll
        for (int tn = 0; tn < 4; ++tn) {
            int R0 = 16 * tm + qd * 4, Cc = 16 * tn + cl;
            f16x4v p;
            p[0] = (f16)C[tm][tn][0]; p[1] = (f16)C[tm][tn][1];
            p[2] = (f16)C[tm][tn][2]; p[3] = (f16)C[tm][tn][3];
            *(f16x4v*)&Ws[Cc * LDP + R0] = p;
        }
}

// store with per-R scale (used to fold Lambda^{1/2} into the transpose store)
__device__ __forceinline__ void store_cm_s(f16* Ws, const f32x4v C[4][4], const float2 lrow[4][4]) {
    const int lane = threadIdx.x & 63;
    const int cl = lane & 15, qd = lane >> 4;
    #pragma unroll
    for (int tm = 0; tm < 4; ++tm)
        #pragma unroll
        for (int tn = 0; tn < 4; ++tn) {
            int R0 = 16 * tm + qd * 4, Cc = 16 * tn + cl;
            f16x4v p;
            #pragma unroll
            for (int i = 0; i < 4; ++i) p[i] = (f16)(C[tm][tn][i] * sqrtf(lrow[tm][i].x));
            *(f16x4v*)&Ws[Cc * LDP + R0] = p;
        }
}

// ===================== per-iteration batch kernel: J partials =====================
// M_b = w0^2 (I+d) X_b (I+d);  in U-basis: Lam + delta, delta = (la+lc)*dt + (dt Lam dt)
// with dt = U^T d U.  L_offdiag = dd(la,lc)*delta, L_diag = log(la) + log1p(delta_ii/la).
// J_b(no-scalar) = U L U^T.  Accumulate over 8 b's per wave.
__global__ __launch_bounds__(64) void k_batch(const f16* __restrict__ U, const f16* __restrict__ UT,
                                              const float2* __restrict__ lam, const f16* __restrict__ dmat,
                                              float* __restrict__ Jpart) {
    __shared__ __align__(16) f16 sD[64 * LDP];
    __shared__ __align__(16) f16 sU[64 * LDP];
    __shared__ __align__(16) f16 sUT[64 * LDP];
    __shared__ __align__(16) f16 sW[64 * LDP];
    const int lane = threadIdx.x;
    const int cl = lane & 15, qd = lane >> 4;

    #pragma unroll
    for (int t = 0; t < 8; ++t) {
        int k = t * 64 + lane;
        int row = k >> 3, off = (k & 7) << 3;
        *(f16x8v*)&sD[row * LDP + off] = *(const f16x8v*)(dmat + ((size_t)k << 3));
    }
    __syncthreads();

    f32x4v acc[4][4];
    #pragma unroll
    for (int a = 0; a < 4; ++a)
        #pragma unroll
        for (int c = 0; c < 4; ++c) acc[a][c] = f32x4v{0.f, 0.f, 0.f, 0.f};

    for (int bi = 0; bi < 8; ++bi) {
        int b = blockIdx.x * 8 + bi;
        const f16* Ub = U + (size_t)b * 4096;
        const f16* UTb = UT + (size_t)b * 4096;
        #pragma unroll
        for (int t = 0; t < 8; ++t) {
            int k = t * 64 + lane;
            int row = k >> 3, off = (k & 7) << 3;
            *(f16x8v*)&sU[row * LDP + off]  = *(const f16x8v*)(Ub + ((size_t)k << 3));
            *(f16x8v*)&sUT[row * LDP + off] = *(const f16x8v*)(UTb + ((size_t)k << 3));
        }
        const float2* lb = lam + (size_t)b * 64;
        float2 lcol[4], lrow[4][4];
        #pragma unroll
        for (int tn = 0; tn < 4; ++tn) lcol[tn] = lb[16 * tn + cl];
        #pragma unroll
        for (int tm = 0; tm < 4; ++tm)
            #pragma unroll
            for (int i = 0; i < 4; ++i) lrow[tm][i] = lb[16 * tm + qd * 4 + i];
        __syncthreads();

        f32x4v C1[4][4];
        wave_gemm(sD, sUT, C1, true);      // d*U
        __syncthreads();
        store_cm(sW, C1);                  // sW = (dU)^T = U^T d  (row-major)
        __syncthreads();
        f32x4v C2[4][4];
        wave_gemm(sW, sUT, C2, true);      // dt = U^T d U  (symmetric)
        __syncthreads();
        store_cm_s(sW, C2, lrow);          // sW = (Lam^{1/2} dt)^T = dt Lam^{1/2}  (row-major)
        __syncthreads();
        f32x4v C3[4][4];
        wave_gemm(sW, sW, C3, true);       // P = dt Lam dt
        // L = logLam*I + dd o delta,  delta = (la+lc)*dt + P ; exact diagonal via log1p
        #pragma unroll
        for (int tm = 0; tm < 4; ++tm)
            #pragma unroll
            for (int tn = 0; tn < 4; ++tn)
                #pragma unroll
                for (int i = 0; i < 4; ++i) {
                    float la = lrow[tm][i].x, lla = lrow[tm][i].y;
                    float lc = lcol[tn].x,  llc = lcol[tn].y;
                    float delta = (la + lc) * C2[tm][tn][i] + C3[tm][tn][i];
                    int R = 16 * tm + qd * 4 + i, Cc = 16 * tn + cl;
                    float Lv;
                    if (R == Cc) {
                        Lv = lla + log1pf(fmaxf(delta / la, -0.9999f));
                    } else {
                        float u = la - lc;
                        float dd = (fabsf(u) > 1e-3f * (la + lc)) ? (lla - llc) / u : 2.0f / (la + lc);
                        Lv = dd * delta;
                    }
                    C3[tm][tn][i] = Lv;
                }
        __syncthreads();
        store_cm(sW, C3);                  // L (symmetric) row-major
        __syncthreads();
        f32x4v C4[4][4];
        wave_gemm(sW, sU, C4, true);       // L*U^T
        __syncthreads();
        store_cm(sW, C4);                  // sW = (L U^T)^T = U L (row-major)
        __syncthreads();
        wave_gemm(sW, sU, acc, false);     // += (U L)*U^T
        __syncthreads();
    }
    float* Jp = Jpart + (size_t)blockIdx.x * 4096;
    #pragma unroll
    for (int tm = 0; tm < 4; ++tm)
        #pragma unroll
        for (int tn = 0; tn < 4; ++tn)
            #pragma unroll
            for (int i = 0; i < 4; ++i) {
                int R = 16 * tm + qd * 4 + i, Cc = 16 * tn + cl;
                Jp[R * 64 + Cc] = acc[tm][tn][i];
            }
}

// 64 blocks: blockIdx&15 selects the 256-element slice, blockIdx>>4 the partial
// quarter. Writes 4 quarter-sums into Jq[4][4096] (the idle mpart region).
// r5: 16-block version used 6% of CUs for a 16.7MB read (~26us/call).
__global__ __launch_bounds__(256) void k_jred(const float* __restrict__ Jpart, float* __restrict__ Jq) {
    int e = (blockIdx.x & 15) * 256 + threadIdx.x;
    int pq = blockIdx.x >> 4;
    float s = 0.0f;
    for (int p = pq * 256; p < pq * 256 + 256; ++p) s += Jpart[(size_t)p * 4096 + e];
    Jq[(size_t)pq * 4096 + e] = s;
}

// ===================== fused: J finalize + exp + mean update + next-iter prep =====================
__global__ __launch_bounds__(256) void k_upstep(const float* __restrict__ Jq, float* __restrict__ C12g,
                                                float* __restrict__ meang, float* __restrict__ state,
                                                f16* __restrict__ d16) {
    __shared__ float buf[3 * 4096];
    __shared__ float red[256];
    float *BA = buf, *BB = buf + 4096, *BC = buf + 8192;
    int tid = threadIdx.x;
    float lw0 = state[2];
    float nu = state[0], tau = state[1];
    float c2 = 0.0f, trv = 0.0f;
    for (int idx = tid; idx < 4096; idx += 256) {
        float js = Jq[idx] + Jq[4096 + idx] + Jq[8192 + idx] + Jq[12288 + idx];
        float v = js * (1.0f / 8192.0f) + ((idx % 65 == 0) ? 2.0f * lw0 : 0.0f);
        BA[idx] = v;
        c2 += v * v;
        if (idx % 65 == 0) trv += v;
    }
    c2 = bred256(c2, red);
    trv = bred256(trv, red);
    float crit = sqrtf(c2);
    float cc = trv / 64.0f;
    float h = nu * crit;
    // G = nu*(J - c I); exp(nu J) = e^{nu c} * (I + G + G^2/2 + G^3/6 + G^4/24)
    for (int idx = tid; idx < 4096; idx += 256)
        BA[idx] = nu * (BA[idx] - ((idx % 65 == 0) ? cc : 0.0f));
    g64(BA, BA, BB, 1.0f, false);                                   // G^2
    for (int idx = tid; idx < 4096; idx += 256)
        BC[idx] = ((idx % 65 == 0) ? 1.0f : 0.0f) + BA[idx] + 0.5f * BB[idx];
    g64(BB, BA, BC, 1.0f / 6.0f, true);                             // + G^3/6
    g64(BB, BB, BC, 1.0f / 24.0f, true);                            // + G^4/24
    float sc = expf(nu * cc);
    for (int idx = tid; idx < 4096; idx += 256) BC[idx] *= sc;      // E = exp(nu J)
    __syncthreads();
    for (int idx = tid; idx < 4096; idx += 256) BA[idx] = C12g[idx];
    g64(BA, BC, BB, 1.0f, false);                                   // T = C12 * E
    g64(BB, BA, BC, 1.0f, false);                                   // mean' = T * C12
    for (int idx = tid; idx < 4096; idx += 256) meang[idx] = BC[idx];
    if (tid == 0) {
        if (h < tau) { state[0] = 0.95f * nu; state[1] = h; }
        else         { state[0] = 0.5f * nu; }
    }
    __syncthreads();
    // prep for the next iteration: consumes mean' in BC, overwrites BA/BB, writes d16 + new C12
    prep_core(BC, BA, BB, red, d16, C12g, state);
}

// ===================== final: P = sqrt(bias) * mean^{-1/2} =====================
__global__ __launch_bounds__(256) void k_final_prep(const float* __restrict__ mean, const float* __restrict__ S,
                                                    f16* __restrict__ P16) {
    __shared__ float buf[3 * 4096];
    __shared__ float red[256];
    float *BA = buf, *BB = buf + 4096, *BC = buf + 8192;
    int tid = threadIdx.x;
    float tr = 0.0f;
    for (int idx = tid; idx < 4096; idx += 256) {
        float v = mean[idx]; BA[idx] = v;
        if (idx % 65 == 0) tr += v;
    }
    tr = bred256(tr, red);
    float g = tr / 64.0f, invg = 1.0f / g;
    for (int idx = tid; idx < 4096; idx += 256)
        BA[idx] = BA[idx] * invg - ((idx % 65 == 0) ? 1.0f : 0.0f);
    g64(BA, BA, BB, 1.0f, false);
    for (int idx = tid; idx < 4096; idx += 256)
        BC[idx] = ((idx % 65 == 0) ? 1.0f : 0.0f) - 0.5f * BA[idx] + 0.375f * BB[idx];
    g64(BB, BA, BC, -0.3125f, true);
    g64(BB, BB, BC, 0.2734375f, true);       // BC = (I+eps)^{-1/2}
    float w0 = rsqrtf(g);
    g64(S, BC, BA, w0, false);               // P = w0 * S * BC  (S read from global)
    for (int idx = tid; idx < 4096; idx += 256) P16[idx] = (f16)BA[idx];
}

// ===================== output: Y_b = P X_b P^T =====================
__global__ __launch_bounds__(64) void k_out(const float* __restrict__ X, const f16* __restrict__ P16,
                                            float* __restrict__ out) {
    __shared__ __align__(16) f16 sP[64 * LDP];
    __shared__ __align__(16) f16 sX[64 * LDP];
    __shared__ __align__(16) f16 sW[64 * LDP];
    const int lane = threadIdx.x;
    const int cl = lane & 15, qd = lane >> 4;
    #pragma unroll
    for (int t = 0; t < 8; ++t) {
        int k = t * 64 + lane;
        int row = k >> 3, off = (k & 7) << 3;
        *(f16x8v*)&sP[row * LDP + off] = *(const f16x8v*)(P16 + ((size_t)k << 3));
    }
    __syncthreads();
    for (int bi = 0; bi < 4; ++bi) {
        int b = blockIdx.x * 4 + bi;
        const float* Xb = X + (size_t)b * 4096;
        #pragma unroll
        for (int t = 0; t < 16; ++t) {
            int k = t * 64 + lane;               // float4 chunk
            float4 v = ((const float4*)Xb)[k];
            int row = k >> 4, off = (k & 15) << 2;
            f16x4v h; h[0] = (f16)v.x; h[1] = (f16)v.y; h[2] = (f16)v.z; h[3] = (f16)v.w;
            *(f16x4v*)&sX[row * LDP + off] = h;
        }
        __syncthreads();
        f32x4v C1[4][4];
        wave_gemm(sX, sP, C1, true);          // X * P^T (X symmetric)
        __syncthreads();
        store_cm(sW, C1);                      // sW = (X P^T)^T = P X
        __syncthreads();
        f32x4v C2[4][4];
        wave_gemm(sW, sP, C2, true);           // (P X) * P^T = Y
        float* ob = out + (size_t)b * 4096;
        #pragma unroll
        for (int tm = 0; tm < 4; ++tm)
            #pragma unroll
            for (int tn = 0; tn < 4; ++tn)
                #pragma unroll
                for (int i = 0; i < 4; ++i) {
                    int R = 16 * tm + qd * 4 + i, Cc = 16 * tn + cl;
                    ob[R * 64 + Cc] = C2[tm][tn][i];
                }
        __syncthreads();
    }
}

// ===================== host =====================
extern "C" void kernel_launch(void* const* d_in, const int* in_sizes, int n_in,
                              void* d_out, int out_size, void* d_ws, size_t ws_size,
                              hipStream_t stream) {
    const float* X    = (const float*)d_in[0];
    const float* bias = (const float*)d_in[1];
    float* out = (float*)d_out;
    uint8_t* w = (uint8_t*)d_ws;

    f16*    U     = (f16*)(w + OFF_U);
    f16*    UT    = (f16*)(w + OFF_UT);
    float2* lam   = (float2*)(w + OFF_LAM);
    float*  mpart = (float*)(w + OFF_MPART);   // reused as Jq[4][4096] in the iteration loop
    float*  Jpart = (float*)(w + OFF_JPART);
    float*  mean  = (float*)(w + OFF_MEAN);
    float*  C12   = (float*)(w + OFF_C12);
    float*  S     = (float*)(w + OFF_S);
    f16*    P16   = (f16*)(w + OFF_P16);
    f16*    d16   = (f16*)(w + OFF_D16);
    float*  state = (float*)(w + OFF_STATE);

    k_mean_part<<<64, 256, 0, stream>>>(X, mpart);
    k_mean_fin<<<16, 256, 0, stream>>>(mpart, mean);
    k_init<<<1, 64, 0, stream>>>(state);
    k_bias_sqrt<<<1, 256, 0, stream>>>(bias, S);
    k_eig<<<8192, 64, 0, stream>>>(X, U, UT, lam);
    k_prep<<<1, 256, 0, stream>>>(mean, d16, C12, state);
    for (int it = 0; it < 5; ++it) {
        k_batch<<<1024, 64, 0, stream>>>(U, UT, lam, d16, Jpart);
        k_jred<<<64, 256, 0, stream>>>(Jpart, mpart);
        k_upstep<<<1, 256, 0, stream>>>(mpart, C12, mean, state, d16);
    }
    k_final_prep<<<1, 256, 0, stream>>>(mean, S, P16);
    k_out<<<2048, 64, 0, stream>>>(X, P16, out);
}